// Round 13
// baseline (6228.764 us; speedup 1.0000x reference)
//
#include <hip/hip_runtime.h>
#include <hip/hip_fp16.h>

typedef __attribute__((ext_vector_type(8))) short s16x8;
typedef __attribute__((ext_vector_type(8))) _Float16 f16x8;
typedef __attribute__((ext_vector_type(4))) float f32x4;

// ---------------------------------------------------------------------------
// fp32 -> fp16 conversion (vectorized, grid-stride)
// ---------------------------------------------------------------------------
__global__ void cvt_f32_to_f16_kernel(const float* __restrict__ in,
                                      __half* __restrict__ out, long n) {
  long i = (long)blockIdx.x * blockDim.x + threadIdx.x;
  long stride = (long)gridDim.x * blockDim.x;
  const float4* p4 = (const float4*)in;
  for (long j = i; j * 8 < n; j += stride) {
    float4 a = p4[j * 2];
    float4 b = p4[j * 2 + 1];
    union { s16x8 v; __half2 h2[4]; } w;
    w.h2[0] = __floats2half2_rn(a.x, a.y);
    w.h2[1] = __floats2half2_rn(a.z, a.w);
    w.h2[2] = __floats2half2_rn(b.x, b.y);
    w.h2[3] = __floats2half2_rn(b.z, b.w);
    *(s16x8*)(out + j * 8) = w.v;
  }
}

// ---------------------------------------------------------------------------
// Dequant 8 int4-in-int32 -> 8 fp16: f16(64+q)=0x5400|(q<<4); w = b*s-(64+z)*s
// ---------------------------------------------------------------------------
__device__ __forceinline__ s16x8 dq_compute(int4 q0, int4 q1, float s, float z) {
  __half hs = __float2half(s);
  __half2 s2 = __halves2half2(hs, hs);
  __half hc = __float2half(-(64.f + z) * s);
  __half2 c2 = __halves2half2(hc, hc);
  uint32_t b0 = 0x54005400u + ((uint32_t)q0.x << 4) + ((uint32_t)q0.y << 20);
  uint32_t b1 = 0x54005400u + ((uint32_t)q0.z << 4) + ((uint32_t)q0.w << 20);
  uint32_t b2 = 0x54005400u + ((uint32_t)q1.x << 4) + ((uint32_t)q1.y << 20);
  uint32_t b3 = 0x54005400u + ((uint32_t)q1.z << 4) + ((uint32_t)q1.w << 20);
  union { s16x8 v; __half2 h2[4]; } w;
  w.h2[0] = __hfma2(*(__half2*)&b0, s2, c2);
  w.h2[1] = __hfma2(*(__half2*)&b1, s2, c2);
  w.h2[2] = __hfma2(*(__half2*)&b2, s2, c2);
  w.h2[3] = __hfma2(*(__half2*)&b3, s2, c2);
  return w.v;
}

// bijective XCD swizzle (m204): consecutive logical ids land on the same XCD.
__device__ __forceinline__ int xcd_swz(int w0, int nwg) {
  const int q = nwg >> 3, r = nwg & 7;
  const int xcd = w0 & 7, idx = w0 >> 3;
  const int base = (xcd < r) ? xcd * (q + 1) : r * (q + 1) + (xcd - r) * q;
  return base + idx;
}

// ---------------------------------------------------------------------------
// gate/up GEMM, M-chunked, full-I: P = Xh @ Wq^T (dequant inline).
// EPI=0: Pan = fp16(acc).  EPI=1: Pan = silu(Pan) * acc  (in-place h)
// BM=256, BN=128, BK=64. 512 thr (8 waves: 4M x 2N, 64x64 each).
// A fragments REGISTER-prefetched in MFMA layout (2-deep) -- A never in LDS.
// B: dequant -> LDS dbuf (32 KB), 2-deep Q reg prefetch. 1 barrier / K-tile.
// ---------------------------------------------------------------------------
template <int EPI>
__global__ __launch_bounds__(512, 2)
void qgemm_x_kernel(const __half* __restrict__ Xh,
                    const int* __restrict__ Q,
                    const float* __restrict__ S, const float* __restrict__ Z,
                    __half* __restrict__ Pan, int mbs) {
  constexpr int H = 4096, I = 11008, G = 32;
  const int wg = xcd_swz(blockIdx.x, gridDim.x);
  const int mb = wg % mbs;          // mb fastest: neighbors share the W panel
  const int nb = wg / mbs;
  const int m0 = mb * 256;
  const int n0 = nb * 128;
  const int tid = threadIdx.x;
  const int lane = tid & 63;
  const int wave = tid >> 6;
  const int wm = (wave >> 1) * 64, wn = (wave & 1) * 64;
  const int l15 = lane & 15, lq = lane >> 4;
  const int rsw = (l15 & 7) << 3;

  __shared__ __half Bs[2][128][64];   // 32 KB

  f32x4 acc[4][4];
#pragma unroll
  for (int i = 0; i < 4; ++i)
#pragma unroll
    for (int j = 0; j < 4; ++j) acc[i][j] = {0.f, 0.f, 0.f, 0.f};

  // A fragment base: row m0+wm+l15 (+i*16), col lq*8 (+t*64+kk*32)
  const __half* aP = Xh + (size_t)(m0 + wm + l15) * H + lq * 8;
  // B staging: 512 thr cover 128 rows x 64 cols
  const int qrow = tid >> 2, qcol0 = (tid & 3) * 16, qsw = (qrow & 7) << 3;
  const int*   qP = Q + (size_t)(n0 + qrow) * H + qcol0;
  const float* sP = S + (size_t)(n0 + qrow) * G;
  const float* zP = Z + (size_t)(n0 + qrow) * G;

  // 2-deep named prefetch sets (static indexing only)
  f16x8 fA[8], fB[8];
  int4  qA[4], qB[4];
  float sA, zA, sB, zB;

#define LOAD_AF(set, kk)                                              \
  {                                                                   \
    const int _k = (kk);                                              \
    _Pragma("unroll")                                                 \
    for (int i = 0; i < 4; ++i) {                                     \
      f##set[i * 2 + 0] = *(const f16x8*)(aP + (size_t)i * 16 * H + _k);      \
      f##set[i * 2 + 1] = *(const f16x8*)(aP + (size_t)i * 16 * H + _k + 32); \
    }                                                                 \
  }
#define LOAD_Q(set, kk)                                               \
  {                                                                   \
    const int _k = (kk);                                              \
    _Pragma("unroll")                                                 \
    for (int i = 0; i < 4; ++i) q##set[i] = ((const int4*)(qP + _k))[i]; \
    s##set = sP[_k >> 7]; z##set = zP[_k >> 7];                       \
  }
#define WRITE_B(buf, set)                                             \
  {                                                                   \
    *(s16x8*)&Bs[buf][qrow][(qcol0 + 0) ^ qsw] = dq_compute(q##set[0], q##set[1], s##set, z##set); \
    *(s16x8*)&Bs[buf][qrow][(qcol0 + 8) ^ qsw] = dq_compute(q##set[2], q##set[3], s##set, z##set); \
  }
#define MFMA_BUF(buf, set)                                            \
  {                                                                   \
    __builtin_amdgcn_s_setprio(1);                                    \
    _Pragma("unroll")                                                 \
    for (int kk = 0; kk < 2; ++kk) {                                  \
      const int cbase = (kk * 32 + lq * 8) ^ rsw;                     \
      _Pragma("unroll")                                               \
      for (int j = 0; j < 4; ++j) {                                   \
        f16x8 bf = *(const f16x8*)&Bs[buf][wn + j * 16 + l15][cbase]; \
        _Pragma("unroll")                                             \
        for (int i = 0; i < 4; ++i)                                   \
          acc[i][j] = __builtin_amdgcn_mfma_f32_16x16x32_f16(f##set[i * 2 + kk], bf, acc[i][j], 0, 0, 0); \
      }                                                               \
    }                                                                 \
    __builtin_amdgcn_s_setprio(0);                                    \
  }

  const int nt = H / 64;  // 64, even
  // ---- prologue: A-frags + Q for tiles 0,1; B(0) -> LDS ----
  LOAD_AF(A, 0)
  LOAD_AF(B, 64)
  LOAD_Q(A, 0)
  LOAD_Q(B, 64)
  WRITE_B(0, A)
  __syncthreads();

  for (int t = 0; t < nt; t += 2) {
    if (t + 2 < nt) LOAD_Q(A, (t + 2) * 64)
    MFMA_BUF(0, A)                               // tile t (A-frags in regs)
    if (t + 2 < nt) LOAD_AF(A, (t + 2) * 64)     // fA free now; ~800cyc to use
    WRITE_B(1, B)                                // tile t+1 B -> LDS
    __syncthreads();
    if (t + 3 < nt) LOAD_Q(B, (t + 3) * 64)
    MFMA_BUF(1, B)                               // tile t+1
    if (t + 3 < nt) LOAD_AF(B, (t + 3) * 64)
    if (t + 2 < nt) WRITE_B(0, A)                // tile t+2 B -> LDS
    __syncthreads();
  }
#undef LOAD_AF
#undef LOAD_Q
#undef WRITE_B
#undef MFMA_BUF

  // ---- epilogue ----
#pragma unroll
  for (int i = 0; i < 4; ++i)
#pragma unroll
    for (int j = 0; j < 4; ++j)
#pragma unroll
      for (int r = 0; r < 4; ++r) {
        const int row = m0 + wm + i * 16 + lq * 4 + r;
        const int col = n0 + wn + j * 16 + l15;
        const size_t idx = (size_t)row * I + col;
        if (EPI == 0) {
          Pan[idx] = __float2half(acc[i][j][r]);
        } else {
          float g = __half2float(Pan[idx]);
          float u = acc[i][j][r];
          Pan[idx] = __float2half((g / (1.f + __expf(-g))) * u);
        }
      }
}

// ---------------------------------------------------------------------------
// Down GEMM, M-chunked, full-K: out = h @ Wd^T. Same structure. K=11008.
// ---------------------------------------------------------------------------
__global__ __launch_bounds__(512, 2)
void down_kernel(const __half* __restrict__ Hws,
                 const int* __restrict__ Qd,
                 const float* __restrict__ Sd, const float* __restrict__ Zd,
                 float* __restrict__ Out, int mbs) {
  constexpr int K = 11008, N = 4096, G = 86;
  const int wg = xcd_swz(blockIdx.x, gridDim.x);
  const int mb = wg % mbs;
  const int nb = wg / mbs;
  const int m0 = mb * 256, n0 = nb * 128;
  const int tid = threadIdx.x;
  const int lane = tid & 63;
  const int wave = tid >> 6;
  const int wm = (wave >> 1) * 64, wn = (wave & 1) * 64;
  const int l15 = lane & 15, lq = lane >> 4;
  const int rsw = (l15 & 7) << 3;

  __shared__ __half Bs[2][128][64];

  f32x4 acc[4][4];
#pragma unroll
  for (int i = 0; i < 4; ++i)
#pragma unroll
    for (int j = 0; j < 4; ++j) acc[i][j] = {0.f, 0.f, 0.f, 0.f};

  const __half* aP = Hws + (size_t)(m0 + wm + l15) * K + lq * 8;
  const int qrow = tid >> 2, qcol0 = (tid & 3) * 16, qsw = (qrow & 7) << 3;
  const int*   qP = Qd + (size_t)(n0 + qrow) * K + qcol0;
  const float* sP = Sd + (size_t)(n0 + qrow) * G;
  const float* zP = Zd + (size_t)(n0 + qrow) * G;

  f16x8 fA[8], fB[8];
  int4  qA[4], qB[4];
  float sA, zA, sB, zB;

#define LOAD_AF(set, kk)                                              \
  {                                                                   \
    const int _k = (kk);                                              \
    _Pragma("unroll")                                                 \
    for (int i = 0; i < 4; ++i) {                                     \
      f##set[i * 2 + 0] = *(const f16x8*)(aP + (size_t)i * 16 * K + _k);      \
      f##set[i * 2 + 1] = *(const f16x8*)(aP + (size_t)i * 16 * K + _k + 32); \
    }                                                                 \
  }
#define LOAD_Q(set, kk)                                               \
  {                                                                   \
    const int _k = (kk);                                              \
    _Pragma("unroll")                                                 \
    for (int i = 0; i < 4; ++i) q##set[i] = ((const int4*)(qP + _k))[i]; \
    s##set = sP[_k >> 7]; z##set = zP[_k >> 7];                       \
  }
#define WRITE_B(buf, set)                                             \
  {                                                                   \
    *(s16x8*)&Bs[buf][qrow][(qcol0 + 0) ^ qsw] = dq_compute(q##set[0], q##set[1], s##set, z##set); \
    *(s16x8*)&Bs[buf][qrow][(qcol0 + 8) ^ qsw] = dq_compute(q##set[2], q##set[3], s##set, z##set); \
  }
#define MFMA_BUF(buf, set)                                            \
  {                                                                   \
    __builtin_amdgcn_s_setprio(1);                                    \
    _Pragma("unroll")                                                 \
    for (int kk = 0; kk < 2; ++kk) {                                  \
      const int cbase = (kk * 32 + lq * 8) ^ rsw;                     \
      _Pragma("unroll")                                               \
      for (int j = 0; j < 4; ++j) {                                   \
        f16x8 bf = *(const f16x8*)&Bs[buf][wn + j * 16 + l15][cbase]; \
        _Pragma("unroll")                                             \
        for (int i = 0; i < 4; ++i)                                   \
          acc[i][j] = __builtin_amdgcn_mfma_f32_16x16x32_f16(f##set[i * 2 + kk], bf, acc[i][j], 0, 0, 0); \
      }                                                               \
    }                                                                 \
    __builtin_amdgcn_s_setprio(0);                                    \
  }

  const int nt = K / 64;  // 172, even
  LOAD_AF(A, 0)
  LOAD_AF(B, 64)
  LOAD_Q(A, 0)
  LOAD_Q(B, 64)
  WRITE_B(0, A)
  __syncthreads();

  for (int t = 0; t < nt; t += 2) {
    if (t + 2 < nt) LOAD_Q(A, (t + 2) * 64)
    MFMA_BUF(0, A)
    if (t + 2 < nt) LOAD_AF(A, (t + 2) * 64)
    WRITE_B(1, B)
    __syncthreads();
    if (t + 3 < nt) LOAD_Q(B, (t + 3) * 64)
    MFMA_BUF(1, B)
    if (t + 3 < nt) LOAD_AF(B, (t + 3) * 64)
    if (t + 2 < nt) WRITE_B(0, A)
    __syncthreads();
  }
#undef LOAD_AF
#undef LOAD_Q
#undef WRITE_B
#undef MFMA_BUF

#pragma unroll
  for (int i = 0; i < 4; ++i)
#pragma unroll
    for (int j = 0; j < 4; ++j)
#pragma unroll
      for (int r = 0; r < 4; ++r) {
        const int row = m0 + wm + i * 16 + lq * 4 + r;
        const int col = n0 + wn + j * 16 + l15;
        Out[(size_t)row * N + col] = acc[i][j][r];
      }
}

// ---------------------------------------------------------------------------
extern "C" void kernel_launch(void* const* d_in, const int* in_sizes, int n_in,
                              void* d_out, int out_size, void* d_ws, size_t ws_size,
                              hipStream_t stream) {
  const float* x  = (const float*)d_in[0];
  const int* qg   = (const int*)d_in[1];
  const int* qu   = (const int*)d_in[2];
  const int* qd   = (const int*)d_in[3];
  const float* sg = (const float*)d_in[4];
  const float* zg = (const float*)d_in[5];
  const float* su = (const float*)d_in[6];
  const float* zu = (const float*)d_in[7];
  const float* sd = (const float*)d_in[8];
  const float* zd = (const float*)d_in[9];
  float* out = (float*)d_out;

  const int M = 8192, H = 4096, I = 11008;

  // M-chunking: x fp16 chunk + h panel chunk in ws. Mc multiple of 256.
  const size_t per_row = (size_t)(H + I) * 2;
  long mc = (long)(ws_size / per_row);
  mc &= ~255L;
  if (mc > M) mc = M;
  if (mc < 256) mc = 256;
  const int Mc = (int)mc;

  __half* wsx = (__half*)d_ws;
  __half* wsh = (__half*)((char*)d_ws + (size_t)Mc * H * 2);

  for (int mbase = 0; mbase < M; mbase += Mc) {
    const int rows = (M - mbase < Mc) ? (M - mbase) : Mc;
    const int mbs = rows / 256;
    cvt_f32_to_f16_kernel<<<1024, 256, 0, stream>>>(
        x + (size_t)mbase * H, wsx, (long)rows * H);
    qgemm_x_kernel<0><<<mbs * (I / 128), 512, 0, stream>>>(
        wsx, qg, sg, zg, wsh, mbs);
    qgemm_x_kernel<1><<<mbs * (I / 128), 512, 0, stream>>>(
        wsx, qu, su, zu, wsh, mbs);
    down_kernel<<<mbs * (H / 128), 512, 0, stream>>>(
        wsh, qd, sd, zd, out + (size_t)mbase * H, mbs);
  }
}

// Round 14
// 4389.895 us; speedup vs baseline: 1.4189x; 1.4189x over previous
//
#include <hip/hip_runtime.h>
#include <hip/hip_fp16.h>

typedef __attribute__((ext_vector_type(8))) short s16x8;
typedef __attribute__((ext_vector_type(8))) _Float16 f16x8;
typedef __attribute__((ext_vector_type(4))) float f32x4;

// ---------------------------------------------------------------------------
// fp32 -> fp16 conversion (vectorized, grid-stride)
// ---------------------------------------------------------------------------
__global__ void cvt_f32_to_f16_kernel(const float* __restrict__ in,
                                      __half* __restrict__ out, long n) {
  long i = (long)blockIdx.x * blockDim.x + threadIdx.x;
  long stride = (long)gridDim.x * blockDim.x;
  const float4* p4 = (const float4*)in;
  for (long j = i; j * 8 < n; j += stride) {
    float4 a = p4[j * 2];
    float4 b = p4[j * 2 + 1];
    union { s16x8 v; __half2 h2[4]; } w;
    w.h2[0] = __floats2half2_rn(a.x, a.y);
    w.h2[1] = __floats2half2_rn(a.z, a.w);
    w.h2[2] = __floats2half2_rn(b.x, b.y);
    w.h2[3] = __floats2half2_rn(b.z, b.w);
    *(s16x8*)(out + j * 8) = w.v;
  }
}

// ---------------------------------------------------------------------------
// Dequant 8 int4-in-int32 -> 8 fp16: f16(64+q)=0x5400|(q<<4); w = b*s-(64+z)*s
// ---------------------------------------------------------------------------
__device__ __forceinline__ s16x8 dq_compute(int4 q0, int4 q1, float s, float z) {
  __half hs = __float2half(s);
  __half2 s2 = __halves2half2(hs, hs);
  __half hc = __float2half(-(64.f + z) * s);
  __half2 c2 = __halves2half2(hc, hc);
  uint32_t b0 = 0x54005400u + ((uint32_t)q0.x << 4) + ((uint32_t)q0.y << 20);
  uint32_t b1 = 0x54005400u + ((uint32_t)q0.z << 4) + ((uint32_t)q0.w << 20);
  uint32_t b2 = 0x54005400u + ((uint32_t)q1.x << 4) + ((uint32_t)q1.y << 20);
  uint32_t b3 = 0x54005400u + ((uint32_t)q1.z << 4) + ((uint32_t)q1.w << 20);
  union { s16x8 v; __half2 h2[4]; } w;
  w.h2[0] = __hfma2(*(__half2*)&b0, s2, c2);
  w.h2[1] = __hfma2(*(__half2*)&b1, s2, c2);
  w.h2[2] = __hfma2(*(__half2*)&b2, s2, c2);
  w.h2[3] = __hfma2(*(__half2*)&b3, s2, c2);
  return w.v;
}

// bijective XCD swizzle (m204): consecutive logical ids land on the same XCD.
__device__ __forceinline__ int xcd_swz(int w0, int nwg) {
  const int q = nwg >> 3, r = nwg & 7;
  const int xcd = w0 & 7, idx = w0 >> 3;
  const int base = (xcd < r) ? xcd * (q + 1) : r * (q + 1) + (xcd - r) * q;
  return base + idx;
}

// ---------------------------------------------------------------------------
// gate/up GEMM, M-chunked, full-I: P = Xh @ Wq^T (dequant inline).
// EPI=0: Pan = fp16(acc).  EPI=1: Pan = silu(Pan) * acc  (in-place h)
// BM=256, BN=128, BK=64. 512 thr (8 waves: 4M x 2N, 64x64 each).
// A via global_load_lds (dbuf, 1 tile ahead, linear dest + pre-swizzled src).
// B reg-staged (2-deep Q prefetch) + dequant + swizzled ds_write.
// ---------------------------------------------------------------------------
template <int EPI>
__global__ __launch_bounds__(512, 2)
void qgemm_x_kernel(const __half* __restrict__ Xh,
                    const int* __restrict__ Q,
                    const float* __restrict__ S, const float* __restrict__ Z,
                    __half* __restrict__ Pan, int mbs) {
  constexpr int H = 4096, I = 11008, G = 32;
  const int wg = xcd_swz(blockIdx.x, gridDim.x);
  const int mb = wg % mbs;          // mb fastest: neighbors share the W panel
  const int nb = wg / mbs;
  const int m0 = mb * 256;
  const int n0 = nb * 128;
  const int tid = threadIdx.x;
  const int lane = tid & 63;
  const int wave = tid >> 6;
  const int wm = (wave >> 1) * 64, wn = (wave & 1) * 64;
  const int l15 = lane & 15, lq = lane >> 4;
  const int rsw = (l15 & 7) << 3;

  __shared__ __half As[2][256][64];   // 64 KB (DMA-staged)
  __shared__ __half Bs[2][128][64];   // 32 KB

  f32x4 acc[4][4];
#pragma unroll
  for (int i = 0; i < 4; ++i)
#pragma unroll
    for (int j = 0; j < 4; ++j) acc[i][j] = {0.f, 0.f, 0.f, 0.f};

  // A DMA map: granule g = c*512+tid covers row c*64+(tid>>3), slot tid&7.
  // LDS[row][gd] = X[row][gd ^ (row&7)]  (read side XORs back with rsw).
  const int arowD = tid >> 3;                                  // 0..63 (+c*64)
  const int acolD = (((tid & 7) ^ ((tid >> 3) & 7)) << 3);     // element col
  // B staging: 512 thr cover 128 rows x 64 cols
  const int qrow = tid >> 2, qcol0 = (tid & 3) * 16, qsw = (qrow & 7) << 3;
  const int*   qP = Q + (size_t)(n0 + qrow) * H + qcol0;
  const float* sP = S + (size_t)(n0 + qrow) * G;
  const float* zP = Z + (size_t)(n0 + qrow) * G;

  int4 qA[4], qB[4];
  float sA, zA, sB, zB;

#define STAGE_A(buf, kk)                                              \
  {                                                                   \
    const int _k = (kk);                                              \
    _Pragma("unroll")                                                 \
    for (int c = 0; c < 4; ++c) {                                     \
      const __half* src = Xh + (size_t)(m0 + c * 64 + arowD) * H + _k + acolD; \
      __half* dst = &As[buf][0][0] + (size_t)(c * 512 + tid) * 8;     \
      __builtin_amdgcn_global_load_lds((const __attribute__((address_space(1))) void*)src, \
                                       (__attribute__((address_space(3))) void*)dst, 16, 0, 0); \
    }                                                                 \
  }
#define LOAD_Q(set, kk)                                               \
  {                                                                   \
    const int _k = (kk);                                              \
    _Pragma("unroll")                                                 \
    for (int i = 0; i < 4; ++i) q##set[i] = ((const int4*)(qP + _k))[i]; \
    s##set = sP[_k >> 7]; z##set = zP[_k >> 7];                       \
  }
#define WRITE_B(buf, set)                                             \
  {                                                                   \
    *(s16x8*)&Bs[buf][qrow][(qcol0 + 0) ^ qsw] = dq_compute(q##set[0], q##set[1], s##set, z##set); \
    *(s16x8*)&Bs[buf][qrow][(qcol0 + 8) ^ qsw] = dq_compute(q##set[2], q##set[3], s##set, z##set); \
  }
#define MFMA_BUF(buf)                                                 \
  {                                                                   \
    __builtin_amdgcn_s_setprio(1);                                    \
    _Pragma("unroll")                                                 \
    for (int kk = 0; kk < 2; ++kk) {                                  \
      const int cbase = (kk * 32 + lq * 8) ^ rsw;                     \
      f16x8 af[4];                                                    \
      _Pragma("unroll")                                               \
      for (int i = 0; i < 4; ++i)                                     \
        af[i] = *(const f16x8*)&As[buf][wm + i * 16 + l15][cbase];    \
      _Pragma("unroll")                                               \
      for (int j = 0; j < 4; ++j) {                                   \
        f16x8 bf = *(const f16x8*)&Bs[buf][wn + j * 16 + l15][cbase]; \
        _Pragma("unroll")                                             \
        for (int i = 0; i < 4; ++i)                                   \
          acc[i][j] = __builtin_amdgcn_mfma_f32_16x16x32_f16(af[i], bf, acc[i][j], 0, 0, 0); \
      }                                                               \
    }                                                                 \
    __builtin_amdgcn_s_setprio(0);                                    \
  }

  const int nt = H / 64;  // 64, even
  // ---- prologue: A(0) via DMA; Q(0),Q(1) to regs; B(0) -> LDS ----
  STAGE_A(0, 0)
  LOAD_Q(A, 0)
  LOAD_Q(B, 64)
  WRITE_B(0, A)
  __syncthreads();   // drains A-DMA(0) too

  for (int t = 0; t < nt; t += 2) {
    if (t + 1 < nt) STAGE_A(1, (t + 1) * 64)   // in flight during MFMA(t)
    if (t + 2 < nt) LOAD_Q(A, (t + 2) * 64)
    MFMA_BUF(0)                                 // tile t
    if (t + 1 < nt) WRITE_B(1, B)               // tile t+1 B (qB ready)
    __syncthreads();
    if (t + 2 < nt) STAGE_A(0, (t + 2) * 64)
    if (t + 3 < nt) LOAD_Q(B, (t + 3) * 64)
    MFMA_BUF(1)                                 // tile t+1
    if (t + 2 < nt) WRITE_B(0, A)               // tile t+2 B
    __syncthreads();
  }
#undef STAGE_A
#undef LOAD_Q
#undef WRITE_B
#undef MFMA_BUF

  // ---- epilogue ----
#pragma unroll
  for (int i = 0; i < 4; ++i)
#pragma unroll
    for (int j = 0; j < 4; ++j)
#pragma unroll
      for (int r = 0; r < 4; ++r) {
        const int row = m0 + wm + i * 16 + lq * 4 + r;
        const int col = n0 + wn + j * 16 + l15;
        const size_t idx = (size_t)row * I + col;
        if (EPI == 0) {
          Pan[idx] = __float2half(acc[i][j][r]);
        } else {
          float g = __half2float(Pan[idx]);
          float u = acc[i][j][r];
          Pan[idx] = __float2half((g / (1.f + __expf(-g))) * u);
        }
      }
}

// ---------------------------------------------------------------------------
// Down GEMM, M-chunked, full-K: out = h @ Wd^T. Same structure. K=11008.
// ---------------------------------------------------------------------------
__global__ __launch_bounds__(512, 2)
void down_kernel(const __half* __restrict__ Hws,
                 const int* __restrict__ Qd,
                 const float* __restrict__ Sd, const float* __restrict__ Zd,
                 float* __restrict__ Out, int mbs) {
  constexpr int K = 11008, N = 4096, G = 86;
  const int wg = xcd_swz(blockIdx.x, gridDim.x);
  const int mb = wg % mbs;
  const int nb = wg / mbs;
  const int m0 = mb * 256, n0 = nb * 128;
  const int tid = threadIdx.x;
  const int lane = tid & 63;
  const int wave = tid >> 6;
  const int wm = (wave >> 1) * 64, wn = (wave & 1) * 64;
  const int l15 = lane & 15, lq = lane >> 4;
  const int rsw = (l15 & 7) << 3;

  __shared__ __half As[2][256][64];
  __shared__ __half Bs[2][128][64];

  f32x4 acc[4][4];
#pragma unroll
  for (int i = 0; i < 4; ++i)
#pragma unroll
    for (int j = 0; j < 4; ++j) acc[i][j] = {0.f, 0.f, 0.f, 0.f};

  const int arowD = tid >> 3;
  const int acolD = (((tid & 7) ^ ((tid >> 3) & 7)) << 3);
  const int qrow = tid >> 2, qcol0 = (tid & 3) * 16, qsw = (qrow & 7) << 3;
  const int*   qP = Qd + (size_t)(n0 + qrow) * K + qcol0;
  const float* sP = Sd + (size_t)(n0 + qrow) * G;
  const float* zP = Zd + (size_t)(n0 + qrow) * G;

  int4 qA[4], qB[4];
  float sA, zA, sB, zB;

#define STAGE_A(buf, kk)                                              \
  {                                                                   \
    const int _k = (kk);                                              \
    _Pragma("unroll")                                                 \
    for (int c = 0; c < 4; ++c) {                                     \
      const __half* src = Hws + (size_t)(m0 + c * 64 + arowD) * K + _k + acolD; \
      __half* dst = &As[buf][0][0] + (size_t)(c * 512 + tid) * 8;     \
      __builtin_amdgcn_global_load_lds((const __attribute__((address_space(1))) void*)src, \
                                       (__attribute__((address_space(3))) void*)dst, 16, 0, 0); \
    }                                                                 \
  }
#define LOAD_Q(set, kk)                                               \
  {                                                                   \
    const int _k = (kk);                                              \
    _Pragma("unroll")                                                 \
    for (int i = 0; i < 4; ++i) q##set[i] = ((const int4*)(qP + _k))[i]; \
    s##set = sP[_k >> 7]; z##set = zP[_k >> 7];                       \
  }
#define WRITE_B(buf, set)                                             \
  {                                                                   \
    *(s16x8*)&Bs[buf][qrow][(qcol0 + 0) ^ qsw] = dq_compute(q##set[0], q##set[1], s##set, z##set); \
    *(s16x8*)&Bs[buf][qrow][(qcol0 + 8) ^ qsw] = dq_compute(q##set[2], q##set[3], s##set, z##set); \
  }
#define MFMA_BUF(buf)                                                 \
  {                                                                   \
    __builtin_amdgcn_s_setprio(1);                                    \
    _Pragma("unroll")                                                 \
    for (int kk = 0; kk < 2; ++kk) {                                  \
      const int cbase = (kk * 32 + lq * 8) ^ rsw;                     \
      f16x8 af[4];                                                    \
      _Pragma("unroll")                                               \
      for (int i = 0; i < 4; ++i)                                     \
        af[i] = *(const f16x8*)&As[buf][wm + i * 16 + l15][cbase];    \
      _Pragma("unroll")                                               \
      for (int j = 0; j < 4; ++j) {                                   \
        f16x8 bf = *(const f16x8*)&Bs[buf][wn + j * 16 + l15][cbase]; \
        _Pragma("unroll")                                             \
        for (int i = 0; i < 4; ++i)                                   \
          acc[i][j] = __builtin_amdgcn_mfma_f32_16x16x32_f16(af[i], bf, acc[i][j], 0, 0, 0); \
      }                                                               \
    }                                                                 \
    __builtin_amdgcn_s_setprio(0);                                    \
  }

  const int nt = K / 64;  // 172, even
  STAGE_A(0, 0)
  LOAD_Q(A, 0)
  LOAD_Q(B, 64)
  WRITE_B(0, A)
  __syncthreads();

  for (int t = 0; t < nt; t += 2) {
    if (t + 1 < nt) STAGE_A(1, (t + 1) * 64)
    if (t + 2 < nt) LOAD_Q(A, (t + 2) * 64)
    MFMA_BUF(0)
    if (t + 1 < nt) WRITE_B(1, B)
    __syncthreads();
    if (t + 2 < nt) STAGE_A(0, (t + 2) * 64)
    if (t + 3 < nt) LOAD_Q(B, (t + 3) * 64)
    MFMA_BUF(1)
    if (t + 2 < nt) WRITE_B(0, A)
    __syncthreads();
  }
#undef STAGE_A
#undef LOAD_Q
#undef WRITE_B
#undef MFMA_BUF

#pragma unroll
  for (int i = 0; i < 4; ++i)
#pragma unroll
    for (int j = 0; j < 4; ++j)
#pragma unroll
      for (int r = 0; r < 4; ++r) {
        const int row = m0 + wm + i * 16 + lq * 4 + r;
        const int col = n0 + wn + j * 16 + l15;
        Out[(size_t)row * N + col] = acc[i][j][r];
      }
}

// ---------------------------------------------------------------------------
extern "C" void kernel_launch(void* const* d_in, const int* in_sizes, int n_in,
                              void* d_out, int out_size, void* d_ws, size_t ws_size,
                              hipStream_t stream) {
  const float* x  = (const float*)d_in[0];
  const int* qg   = (const int*)d_in[1];
  const int* qu   = (const int*)d_in[2];
  const int* qd   = (const int*)d_in[3];
  const float* sg = (const float*)d_in[4];
  const float* zg = (const float*)d_in[5];
  const float* su = (const float*)d_in[6];
  const float* zu = (const float*)d_in[7];
  const float* sd = (const float*)d_in[8];
  const float* zd = (const float*)d_in[9];
  float* out = (float*)d_out;

  const int M = 8192, H = 4096, I = 11008;

  // M-chunking: x fp16 chunk + h panel chunk in ws. Mc multiple of 256.
  const size_t per_row = (size_t)(H + I) * 2;
  long mc = (long)(ws_size / per_row);
  mc &= ~255L;
  if (mc > M) mc = M;
  if (mc < 256) mc = 256;
  const int Mc = (int)mc;

  __half* wsx = (__half*)d_ws;
  __half* wsh = (__half*)((char*)d_ws + (size_t)Mc * H * 2);

  for (int mbase = 0; mbase < M; mbase += Mc) {
    const int rows = (M - mbase < Mc) ? (M - mbase) : Mc;
    const int mbs = rows / 256;
    cvt_f32_to_f16_kernel<<<1024, 256, 0, stream>>>(
        x + (size_t)mbase * H, wsx, (long)rows * H);
    qgemm_x_kernel<0><<<mbs * (I / 128), 512, 0, stream>>>(
        wsx, qg, sg, zg, wsh, mbs);
    qgemm_x_kernel<1><<<mbs * (I / 128), 512, 0, stream>>>(
        wsx, qu, su, zu, wsh, mbs);
    down_kernel<<<mbs * (H / 128), 512, 0, stream>>>(
        wsh, qd, sd, zd, out + (size_t)mbase * H, mbs);
  }
}